// Round 10
// baseline (224.572 us; speedup 1.0000x reference)
//
#include <hip/hip_runtime.h>
#include <cstdint>

#define NP   4096      // patches
#define DD   768       // embed dim
#define HD   64
#define WD   64
#define KTOP 100
#define BIGL 4097      // N+1

typedef short bf16x8 __attribute__((ext_vector_type(8)));
typedef float f32x4  __attribute__((ext_vector_type(4)));

__device__ __forceinline__ void gload_lds16(const void* g, void* l) {
    __builtin_amdgcn_global_load_lds(
        (const __attribute__((address_space(1))) unsigned int*)(uintptr_t)g,
        (__attribute__((address_space(3))) unsigned int*)(unsigned int)(uintptr_t)l,
        16, 0, 0);
}

__device__ __forceinline__ unsigned short f2bf_rne(float x) {
    unsigned b = __float_as_uint(x);
    unsigned r = b + 0x7FFFu + ((b >> 16) & 1u);
    return (unsigned short)(r >> 16);
}
__device__ __forceinline__ float bf2f(unsigned short h) {
    return __uint_as_float(((unsigned)h) << 16);
}

// ---------------- kernel 1: split A into bf16 hi+lo; zero counts ----------------
__global__ __launch_bounds__(256) void k_split(const float* __restrict__ A,
                                               unsigned short* __restrict__ hi,
                                               unsigned short* __restrict__ lo,
                                               int* __restrict__ counts) {
    if (blockIdx.x < 16) counts[blockIdx.x * 256 + threadIdx.x] = 0;
    int idx = blockIdx.x * 256 + threadIdx.x;       // float4 index
    float4 v = ((const float4*)A)[idx];
    unsigned short h0 = f2bf_rne(v.x), h1 = f2bf_rne(v.y),
                   h2 = f2bf_rne(v.z), h3 = f2bf_rne(v.w);
    unsigned short l0 = f2bf_rne(v.x - bf2f(h0)), l1 = f2bf_rne(v.y - bf2f(h1)),
                   l2 = f2bf_rne(v.z - bf2f(h2)), l3 = f2bf_rne(v.w - bf2f(h3));
    ((ushort4*)hi)[idx] = make_ushort4(h0, h1, h2, h3);
    ((ushort4*)lo)[idx] = make_ushort4(l0, l1, l2, l3);
}

// ---------------- kernel 2: split-bf16 MFMA GEMM ----------------
// Per buffer (32 KB): A-tile then B-tile, each 128 rows x 8 chunks of 16B.
// K-dim packs [hi K=32 | lo K=32]: chunk (row, kcl) with kcl<4 = hi, kcl>=4 = lo.
// Swizzle phys = row*8 + (kcl ^ (row&7)) — R5-proven 0-conflict geometry for both
// the wave-contiguous staging and the 16-row x 4-kc frag ds_read_b128 pattern.
__device__ __forceinline__ void stage_group(const unsigned short* __restrict__ hi,
                                            const unsigned short* __restrict__ lo,
                                            int i0, int j0, int kbase, int tid,
                                            unsigned short* G) {
#pragma unroll
    for (int q = 0; q < 8; ++q) {
        const unsigned short* baseHi = hi + (size_t)(q < 4 ? i0 : j0) * DD + kbase;
        const unsigned short* baseLo = lo + (size_t)(q < 4 ? i0 : j0) * DD + kbase;
        int pp = (q & 3) * 256 + tid;            // phys chunk within tile (0..1023)
        int row = pp >> 3;
        int kcl = (pp & 7) ^ (row & 7);          // logical chunk (inverse of swizzle)
        const unsigned short* src =
            ((kcl < 4) ? baseHi : baseLo) + (size_t)row * DD + (kcl & 3) * 8;
        gload_lds16(src, G + ((q < 4 ? 0 : 1024) + pp) * 8);
    }
}

__global__ __launch_bounds__(256) void k_gemm(const unsigned short* __restrict__ hi,
                                              const unsigned short* __restrict__ lo,
                                              int* __restrict__ counts) {
    __shared__ __align__(16) unsigned short G[2][2048 * 8];   // 2 x 32 KB
    __shared__ int colc[128];
    __shared__ int rowc[128];

    // XCD-locality supertile remap (XCD = blockIdx%8 round-robin):
    int t = ((blockIdx.x & 7) * 66) + (blockIdx.x >> 3);
    int SI = 0, SJ = 0, rem = t;
    for (;;) {
        int sz = (SI == SJ) ? 36 : 64;
        if (rem < sz) break;
        rem -= sz;
        if (++SJ == 4) { ++SI; SJ = SI; }
    }
    int li, lj;
    if (SI == SJ) {
        int r = 0;
        while (rem >= (8 - r)) { rem -= (8 - r); ++r; }
        li = r; lj = r + rem;
    } else { li = rem >> 3; lj = rem & 7; }
    int bi = SI * 8 + li, bj = SJ * 8 + lj;
    int i0 = bi * 128, j0 = bj * 128;

    int tid = threadIdx.x;
    int lane = tid & 63, w = tid >> 6;
    int wm = w & 1, wn = w >> 1;

    f32x4 acc[4][4];
#pragma unroll
    for (int ti = 0; ti < 4; ++ti)
#pragma unroll
        for (int tj = 0; tj < 4; ++tj) { acc[ti][tj][0] = 0.f; acc[ti][tj][1] = 0.f;
                                         acc[ti][tj][2] = 0.f; acc[ti][tj][3] = 0.f; }

    // frag phys-chunk offsets (K-window-independent)
    int kcf = lane >> 4;              // 0..3
    int paH[4], paL[4], pbH[4], pbL[4];
#pragma unroll
    for (int tt = 0; tt < 4; ++tt) {
        int arow = wm * 64 + tt * 16 + (lane & 15);
        paH[tt] = arow * 8 + (kcf ^ (arow & 7));
        paL[tt] = arow * 8 + ((kcf + 4) ^ (arow & 7));
        int brow = wn * 64 + tt * 16 + (lane & 15);
        pbH[tt] = 1024 * 8 / 8 * 8;   // placeholder avoided below
        pbH[tt] = 1024 + brow * 8 + (kcf ^ (brow & 7));
        pbL[tt] = 1024 + brow * 8 + ((kcf + 4) ^ (brow & 7));
    }

    stage_group(hi, lo, i0, j0, 0, tid, G[0]);   // prologue
    for (int it = 0; it < 24; ++it) {
        int cur = it & 1;
        __syncthreads();   // buf[cur] loads done; prev compute on buf[cur^1] done
        if (it + 1 < 24)
            stage_group(hi, lo, i0, j0, (it + 1) * 32, tid, G[cur ^ 1]);
        bf16x8 ahi[4], alo[4], bhi[4], blo[4];
#pragma unroll
        for (int tt = 0; tt < 4; ++tt) {
            ahi[tt] = *(const bf16x8*)&G[cur][paH[tt] * 8];
            alo[tt] = *(const bf16x8*)&G[cur][paL[tt] * 8];
            bhi[tt] = *(const bf16x8*)&G[cur][pbH[tt] * 8];
            blo[tt] = *(const bf16x8*)&G[cur][pbL[tt] * 8];
        }
#pragma unroll
        for (int ti = 0; ti < 4; ++ti)
#pragma unroll
            for (int tj = 0; tj < 4; ++tj) {
                acc[ti][tj] = __builtin_amdgcn_mfma_f32_16x16x32_bf16(
                    ahi[ti], bhi[tj], acc[ti][tj], 0, 0, 0);
                acc[ti][tj] = __builtin_amdgcn_mfma_f32_16x16x32_bf16(
                    alo[ti], bhi[tj], acc[ti][tj], 0, 0, 0);
                acc[ti][tj] = __builtin_amdgcn_mfma_f32_16x16x32_bf16(
                    ahi[ti], blo[tj], acc[ti][tj], 0, 0, 0);
            }
    }

    if (tid < 128) { colc[tid] = 0; rowc[tid] = 0; }
    __syncthreads();

    int nl = lane & 15;
    int rg = lane >> 4;
#pragma unroll
    for (int ti = 0; ti < 4; ++ti)
#pragma unroll
        for (int tj = 0; tj < 4; ++tj) {
            f32x4 a = acc[ti][tj];
            int ct = ((a[0] >= 0.f) ? 1 : 0) + ((a[1] >= 0.f) ? 1 : 0) +
                     ((a[2] >= 0.f) ? 1 : 0) + ((a[3] >= 0.f) ? 1 : 0);
            ct += __shfl_xor(ct, 16);
            ct += __shfl_xor(ct, 32);
            if (rg == 0) atomicAdd(&colc[wn * 64 + tj * 16 + nl], ct);
            if (bi != bj) {
#pragma unroll
                for (int g = 0; g < 4; ++g) {
                    int rv = (a[g] >= 0.f) ? 1 : 0;
                    rv += __shfl_xor(rv, 1);
                    rv += __shfl_xor(rv, 2);
                    rv += __shfl_xor(rv, 4);
                    rv += __shfl_xor(rv, 8);
                    if (nl == 0) atomicAdd(&rowc[wm * 64 + ti * 16 + rg * 4 + g], rv);
                }
            }
        }
    __syncthreads();
    if (tid < 128) {
        atomicAdd(&counts[j0 + tid], colc[tid]);
        if (bi != bj) atomicAdd(&counts[i0 + tid], rowc[tid]);
    }
}

// ---------------- shared helpers ----------------
__device__ __forceinline__ int block_sum256(int v, int lane, int w, int* wred) {
#pragma unroll
    for (int o = 1; o < 64; o <<= 1) v += __shfl_xor(v, o);
    if (lane == 0) wred[w] = v;
    __syncthreads();
    int tt = wred[0] + wred[1] + wred[2] + wred[3];
    __syncthreads();
    return tt;
}
__device__ __forceinline__ int block_exscan256(int v, int lane, int w, int* wred,
                                               int* total) {
    int inc = v;
#pragma unroll
    for (int o = 1; o < 64; o <<= 1) { int u = __shfl_up(inc, o); if (lane >= o) inc += u; }
    if (lane == 63) wred[w] = inc;
    __syncthreads();
    int w0 = wred[0], w1 = wred[1], w2 = wred[2], w3 = wred[3];
    int wofs = (w > 0 ? w0 : 0) + (w > 1 ? w1 : 0) + (w > 2 ? w2 : 0);
    *total = w0 + w1 + w2 + w3;
    __syncthreads();
    return wofs + inc - v;   // exclusive
}

// top-K select + compact into LDS act_s; returns M. Needs wred[4] LDS.
__device__ __forceinline__ int do_select(const float* __restrict__ simrow, int seed,
                                         int tid, int lane, int w, int* wred,
                                         int* act_s) {
    int base = tid * 16;
    unsigned key[16];
#pragma unroll
    for (int n = 0; n < 16; ++n) {
        unsigned b = __float_as_uint(simrow[base + n]);
        key[n] = (b & 0x80000000u) ? ~b : (b | 0x80000000u);   // monotone encode
    }
    unsigned prefix = 0;
    for (int bit = 31; bit >= 0; --bit) {
        unsigned cand = prefix | (1u << bit);
        int c = 0;
#pragma unroll
        for (int n = 0; n < 16; ++n) c += (key[n] >= cand) ? 1 : 0;
        int tot = block_sum256(c, lane, w, wred);
        if (tot >= KTOP) prefix = cand;
    }
    unsigned KT = prefix;
    int cgt = 0, ceq = 0;
#pragma unroll
    for (int n = 0; n < 16; ++n) {
        cgt += (key[n] > KT) ? 1 : 0;
        ceq += (key[n] == KT) ? 1 : 0;
    }
    int totgt = block_sum256(cgt, lane, w, wred);
    int slots = KTOP - totgt;
    int dummy;
    int eqrun = block_exscan256(ceq, lane, w, wred, &dummy);
    int flag[16]; int cf = 0;
#pragma unroll
    for (int n = 0; n < 16; ++n) {
        int j = base + n;
        unsigned k = key[n];
        int topk = (k > KT) || (k == KT && eqrun < slots);
        if (k == KT) ++eqrun;
        int f = (topk && (k >= 0x80000000u || j == seed)) ? 1 : 0;
        flag[n] = f; cf += f;
    }
    int M;
    int off = block_exscan256(cf, lane, w, wred, &M);
#pragma unroll
    for (int n = 0; n < 16; ++n)
        if (flag[n]) act_s[off++] = base + n;
    __syncthreads();
    return M;
}

// ---------------- kernel 3: argmin seed (redundant/block) + simrow + zero outp ----------------
__global__ __launch_bounds__(256) void k_seedrow(const float* __restrict__ A,
                                                 const int* __restrict__ counts,
                                                 const int* __restrict__ attn_seed,
                                                 float* __restrict__ simrow,
                                                 int* __restrict__ seedp,
                                                 int* __restrict__ outp) {
    __shared__ int redA[256], redB[256];
    int tid = threadIdx.x, lane = tid & 63, w = tid >> 6;
    int blk = blockIdx.x;

    int bc = 0x7fffffff, bI = 0;
    for (int j = tid; j < NP; j += 256) {
        int c = counts[j];
        if (c < bc) { bc = c; bI = j; }
    }
    redA[tid] = bc; redB[tid] = bI;
    __syncthreads();
    for (int st = 128; st > 0; st >>= 1) {
        if (tid < st) {
            if (redA[tid + st] < redA[tid] ||
                (redA[tid + st] == redA[tid] && redB[tid + st] < redB[tid])) {
                redA[tid] = redA[tid + st];
                redB[tid] = redB[tid + st];
            }
        }
        __syncthreads();
    }
    int flat = redB[0];
    int sr = flat / WD, sc = flat % WD;
    int vr = sr + attn_seed[0];
    int vc = sc + attn_seed[1];
    int rr, rc;
    if ((vr & 1) == 0) rr = vr >> 1;
    else { int m = vr >> 1; rr = (m & 1) ? m + 1 : m; }   // round-half-to-even
    if ((vc & 1) == 0) rc = vc >> 1;
    else { int m = vc >> 1; rc = (m & 1) ? m + 1 : m; }
    int seed = rr * WD + rc;
    if (blk == 0 && tid == 0) seedp[0] = seed;

    float sv[12];
#pragma unroll
    for (int kk = 0; kk < 12; ++kk) sv[kk] = A[(size_t)seed * DD + lane + kk * 64];
    int jbase = blk * 32 + w * 8;
    for (int jj = 0; jj < 8; ++jj) {
        int j = jbase + jj;
        float sum = 0.f;
#pragma unroll
        for (int kk = 0; kk < 12; ++kk)
            sum += sv[kk] * A[(size_t)j * DD + lane + kk * 64];
#pragma unroll
        for (int o = 32; o > 0; o >>= 1) sum += __shfl_down(sum, o);
        if (lane == 0) simrow[j] = sum;
    }
    if (tid < 32) outp[blk * 32 + tid] = 0;
}

// ---------------- kernel 4: embedded select + subsim rows ----------------
__global__ __launch_bounds__(256) void k_sub(const float* __restrict__ A,
                                             const float* __restrict__ simrow,
                                             const int* __restrict__ seedp,
                                             float* __restrict__ subsim) {
    __shared__ float av[DD];
    __shared__ int wred[4];
    __shared__ int act_s[128];
    int tid = threadIdx.x, lane = tid & 63, w = tid >> 6;
    int p = blockIdx.x;
    int seed = seedp[0];
    int M = do_select(simrow, seed, tid, lane, w, wred, act_s);
    if (p >= M) return;
    int ip = act_s[p];
    for (int k = tid; k < DD; k += 256) av[k] = A[(size_t)ip * DD + k];
    __syncthreads();
    for (int q = w; q < M; q += 4) {
        int iq = act_s[q];
        float sum = 0.f;
#pragma unroll
        for (int kk = 0; kk < 12; ++kk) {
            int k = lane + kk * 64;
            sum += av[k] * A[(size_t)iq * DD + k];
        }
#pragma unroll
        for (int o = 32; o > 0; o >>= 1) sum += __shfl_down(sum, o);
        if (lane == 0) subsim[p * 128 + q] = sum;
    }
}

// ---------------- kernel 5: embedded select + expansion scan + CC (1 block) ----------------
__global__ __launch_bounds__(256) void k_fin(const float* __restrict__ subsim,
                                             const float* __restrict__ simrow,
                                             const int* __restrict__ seedp,
                                             int* __restrict__ outp) {
    __shared__ float ss[128 * 128];   // 64 KB, transposed+rotated
    __shared__ int wred[4];
    __shared__ int act_s[128];
    __shared__ int alive[128];
    __shared__ int lab[128];
    __shared__ unsigned char nbr[128][8];
    __shared__ int ncnt[128];
    __shared__ int chg;
    int tid = threadIdx.x, lane = tid & 63, w = tid >> 6;
    int seed = seedp[0];
    int M = do_select(simrow, seed, tid, lane, w, wred, act_s);

    // ssT(q,p) at ss[q*128 + ((p+q)&127)]: conflict-free writes & column reads
    for (int idx = tid; idx < M * 128; idx += 256) {
        int p = idx >> 7, q = idx & 127;
        ss[q * 128 + ((p + q) & 127)] = subsim[idx];
    }
    __syncthreads();

    // expansion scan with incremental sums
    if (tid < 64) {
        float S_lo = 0.f, S_hi = 0.f;
        for (int q = 0; q < M; ++q) {
            S_lo += ss[q * 128 + ((lane + q) & 127)];
            S_hi += ss[q * 128 + ((lane + 64 + q) & 127)];
        }
        float al = (lane < M) ? 1.f : 0.f;
        float ah = (lane + 64 < M) ? 1.f : 0.f;
        for (int p = 0; p < M; ++p) {
            float Sp = (p < 64) ? __shfl(S_lo, p) : __shfl(S_hi, p - 64);
            if (!(Sp > 0.f)) {   // node p dies: remove its column from all sums
                S_lo -= ss[p * 128 + ((lane + p) & 127)];
                S_hi -= ss[p * 128 + ((lane + 64 + p) & 127)];
                if (lane == p)      al = 0.f;
                if (lane + 64 == p) ah = 0.f;
            }
        }
        alive[lane]      = (lane < M && al != 0.f) ? 1 : 0;
        alive[lane + 64] = (lane + 64 < M && ah != 0.f) ? 1 : 0;
    }
    __syncthreads();

    // CC: neighbor lists + hook/pointer-jump
    if (tid < 128) {
        int a = (tid < M) ? alive[tid] : 0;
        int c = 0;
        if (a) {
            int id = act_s[tid];
            int y = id >> 6, x = id & 63;
            for (int q = 0; q < M; ++q) {
                if (q == tid || !alive[q]) continue;
                int qid = act_s[q];
                int dy = (qid >> 6) - y, dx = (qid & 63) - x;
                if (dy >= -1 && dy <= 1 && dx >= -1 && dx <= 1)
                    nbr[tid][c++] = (unsigned char)q;
            }
        }
        ncnt[tid] = c;
        lab[tid] = a ? tid : 32767;
    }
    __syncthreads();
    while (true) {
        if (tid == 0) chg = 0;
        __syncthreads();
        int local = 0;
        if (tid < M && alive[tid]) {
            int m = lab[tid];
            int nc = ncnt[tid];
            for (int k = 0; k < nc; ++k) { int u = lab[nbr[tid][k]]; if (u < m) m = u; }
            { int u = lab[m]; if (u < m) m = u; }   // jump
            { int u = lab[m]; if (u < m) m = u; }   // jump again
            if (m < lab[tid]) { lab[tid] = m; local = 1; }
        }
        if (local) chg = 1;
        __syncthreads();
        if (chg == 0) break;
        __syncthreads();
    }
    if (tid < M && alive[tid]) outp[act_s[tid]] = act_s[lab[tid]] + 1;
}

extern "C" void kernel_launch(void* const* d_in, const int* in_sizes, int n_in,
                              void* d_out, int out_size, void* d_ws, size_t ws_size,
                              hipStream_t stream) {
    const float* A = (const float*)d_in[0];       // out: (4096, 768) fp32
    const int* attn = (const int*)d_in[1];        // attn_seed: (2,) int32
    int* outp = (int*)d_out;                      // labels: (64,64) int32

    char* ws = (char*)d_ws;
    int*            counts = (int*)(ws);                    // 16 KB
    float*          simrow = (float*)(ws + 16384);          // 16 KB
    int*            seedp  = (int*)(ws + 33284);
    float*          subsim = (float*)(ws + 33792);          // 64 KB
    unsigned short* hi     = (unsigned short*)(ws + 1048576);           // 6.29 MB
    unsigned short* lo     = (unsigned short*)(ws + 1048576 + 6291456); // 6.29 MB

    k_split  <<<3072, 256, 0, stream>>>(A, hi, lo, counts);
    k_gemm   <<<528,  256, 0, stream>>>(hi, lo, counts);
    k_seedrow<<<128,  256, 0, stream>>>(A, counts, attn, simrow, seedp, outp);
    k_sub    <<<128,  256, 0, stream>>>(A, simrow, seedp, subsim);
    k_fin    <<<1,    256, 0, stream>>>(subsim, simrow, seedp, outp);
}

// Round 11
// 192.412 us; speedup vs baseline: 1.1671x; 1.1671x over previous
//
#include <hip/hip_runtime.h>
#include <cstdint>

#define NP   4096      // patches
#define DD   768       // embed dim
#define HD   64
#define WD   64
#define KTOP 100
#define BIGL 4097      // N+1

typedef short bf16x8 __attribute__((ext_vector_type(8)));
typedef float f32x4  __attribute__((ext_vector_type(4)));

__device__ __forceinline__ void gload_lds16(const void* g, void* l) {
    __builtin_amdgcn_global_load_lds(
        (const __attribute__((address_space(1))) unsigned int*)(uintptr_t)g,
        (__attribute__((address_space(3))) unsigned int*)(unsigned int)(uintptr_t)l,
        16, 0, 0);
}

__device__ __forceinline__ unsigned short f2bf_rne(float x) {
    unsigned b = __float_as_uint(x);
    unsigned r = b + 0x7FFFu + ((b >> 16) & 1u);
    return (unsigned short)(r >> 16);
}
__device__ __forceinline__ float bf2f(unsigned short h) {
    return __uint_as_float(((unsigned)h) << 16);
}

// ---------------- kernel 1: split A into bf16 hi+lo; zero counts ----------------
__global__ __launch_bounds__(256) void k_split(const float* __restrict__ A,
                                               unsigned short* __restrict__ hi,
                                               unsigned short* __restrict__ lo,
                                               int* __restrict__ counts) {
    if (blockIdx.x < 16) counts[blockIdx.x * 256 + threadIdx.x] = 0;
    int idx = blockIdx.x * 256 + threadIdx.x;       // float4 index
    float4 v = ((const float4*)A)[idx];
    unsigned short h0 = f2bf_rne(v.x), h1 = f2bf_rne(v.y),
                   h2 = f2bf_rne(v.z), h3 = f2bf_rne(v.w);
    unsigned short l0 = f2bf_rne(v.x - bf2f(h0)), l1 = f2bf_rne(v.y - bf2f(h1)),
                   l2 = f2bf_rne(v.z - bf2f(h2)), l3 = f2bf_rne(v.w - bf2f(h3));
    ((ushort4*)hi)[idx] = make_ushort4(h0, h1, h2, h3);
    ((ushort4*)lo)[idx] = make_ushort4(l0, l1, l2, l3);
}

// ---------------- kernel 2: split-bf16 MFMA GEMM, 512 threads (8 waves) ----------------
// Per buffer (32 KB): A-tile then B-tile, each 128 rows x 8 chunks of 16B.
// K-dim packs [hi K=32 | lo K=32]: chunk (row, kcl): kcl<4 = hi, kcl>=4 = lo.
// Swizzle phys = row*8 + (kcl ^ (row&7)) — measured 0-conflict geometry (R10).
__device__ __forceinline__ void stage_group(const unsigned short* __restrict__ hi,
                                            const unsigned short* __restrict__ lo,
                                            int i0, int j0, int kbase, int tid,
                                            unsigned short* G) {
#pragma unroll
    for (int q = 0; q < 4; ++q) {
        int pp = q * 512 + tid;                  // 0..2047 across both tiles
        int ppt = pp & 1023;
        int row = ppt >> 3;
        int kcl = (ppt & 7) ^ (row & 7);         // logical chunk (inverse of swizzle)
        int rbase = (pp < 1024) ? i0 : j0;
        const unsigned short* src =
            ((kcl < 4) ? hi : lo) + (size_t)(rbase + row) * DD + kbase + (kcl & 3) * 8;
        gload_lds16(src, G + pp * 8);
    }
}

__global__ __launch_bounds__(512, 4) void k_gemm(const unsigned short* __restrict__ hi,
                                                 const unsigned short* __restrict__ lo,
                                                 int* __restrict__ counts) {
    __shared__ __align__(16) unsigned short G[2][2048 * 8];   // 2 x 32 KB
    __shared__ int colc[128];
    __shared__ int rowc[128];

    // XCD-locality supertile remap (XCD = blockIdx%8 round-robin):
    int t = ((blockIdx.x & 7) * 66) + (blockIdx.x >> 3);
    int SI = 0, SJ = 0, rem = t;
    for (;;) {
        int sz = (SI == SJ) ? 36 : 64;
        if (rem < sz) break;
        rem -= sz;
        if (++SJ == 4) { ++SI; SJ = SI; }
    }
    int li, lj;
    if (SI == SJ) {
        int r = 0;
        while (rem >= (8 - r)) { rem -= (8 - r); ++r; }
        li = r; lj = r + rem;
    } else { li = rem >> 3; lj = rem & 7; }
    int bi = SI * 8 + li, bj = SJ * 8 + lj;
    int i0 = bi * 128, j0 = bj * 128;

    int tid = threadIdx.x;
    int lane = tid & 63, w = tid >> 6;   // w 0..7
    int wm = w & 1, wn = w >> 1;         // rows wm*64, cols wn*32

    f32x4 acc[4][2];
#pragma unroll
    for (int ti = 0; ti < 4; ++ti)
#pragma unroll
        for (int u = 0; u < 2; ++u) { acc[ti][u][0] = 0.f; acc[ti][u][1] = 0.f;
                                      acc[ti][u][2] = 0.f; acc[ti][u][3] = 0.f; }

    // frag phys-chunk offsets (K-window-independent)
    int kcf = lane >> 4;                 // 0..3
    int paH[4], paL[4], pbH[2], pbL[2];
#pragma unroll
    for (int tt = 0; tt < 4; ++tt) {
        int arow = wm * 64 + tt * 16 + (lane & 15);
        paH[tt] = arow * 8 + (kcf ^ (arow & 7));
        paL[tt] = arow * 8 + ((kcf + 4) ^ (arow & 7));
    }
#pragma unroll
    for (int u = 0; u < 2; ++u) {
        int brow = wn * 32 + u * 16 + (lane & 15);
        pbH[u] = 1024 + brow * 8 + (kcf ^ (brow & 7));
        pbL[u] = 1024 + brow * 8 + ((kcf + 4) ^ (brow & 7));
    }

    stage_group(hi, lo, i0, j0, 0, tid, G[0]);   // prologue
    for (int it = 0; it < 24; ++it) {
        int cur = it & 1;
        __syncthreads();   // buf[cur] loads done; prev compute on buf[cur^1] done
        if (it + 1 < 24)
            stage_group(hi, lo, i0, j0, (it + 1) * 32, tid, G[cur ^ 1]);
        bf16x8 ahi[4], alo[4], bhi[2], blo[2];
#pragma unroll
        for (int tt = 0; tt < 4; ++tt) {
            ahi[tt] = *(const bf16x8*)&G[cur][paH[tt] * 8];
            alo[tt] = *(const bf16x8*)&G[cur][paL[tt] * 8];
        }
#pragma unroll
        for (int u = 0; u < 2; ++u) {
            bhi[u] = *(const bf16x8*)&G[cur][pbH[u] * 8];
            blo[u] = *(const bf16x8*)&G[cur][pbL[u] * 8];
        }
#pragma unroll
        for (int ti = 0; ti < 4; ++ti)
#pragma unroll
            for (int u = 0; u < 2; ++u) {
                acc[ti][u] = __builtin_amdgcn_mfma_f32_16x16x32_bf16(
                    ahi[ti], bhi[u], acc[ti][u], 0, 0, 0);
                acc[ti][u] = __builtin_amdgcn_mfma_f32_16x16x32_bf16(
                    alo[ti], bhi[u], acc[ti][u], 0, 0, 0);
                acc[ti][u] = __builtin_amdgcn_mfma_f32_16x16x32_bf16(
                    ahi[ti], blo[u], acc[ti][u], 0, 0, 0);
            }
    }

    if (tid < 128) { colc[tid] = 0; rowc[tid] = 0; }
    __syncthreads();

    int nl = lane & 15;     // col within 16x16 tile
    int rg = lane >> 4;     // row group (rows rg*4 + reg)
    int cc[2] = {0, 0};
#pragma unroll
    for (int ti = 0; ti < 4; ++ti)
#pragma unroll
        for (int u = 0; u < 2; ++u) {
            f32x4 a = acc[ti][u];
            cc[u] += ((a[0] >= 0.f) ? 1 : 0) + ((a[1] >= 0.f) ? 1 : 0) +
                     ((a[2] >= 0.f) ? 1 : 0) + ((a[3] >= 0.f) ? 1 : 0);
        }
#pragma unroll
    for (int u = 0; u < 2; ++u) {
        int v = cc[u];
        v += __shfl_xor(v, 16);
        v += __shfl_xor(v, 32);
        if (rg == 0) atomicAdd(&colc[wn * 32 + u * 16 + nl], v);
    }
    if (bi != bj) {
#pragma unroll
        for (int ti = 0; ti < 4; ++ti)
#pragma unroll
            for (int g = 0; g < 4; ++g) {
                int rv = ((acc[ti][0][g] >= 0.f) ? 1 : 0) +
                         ((acc[ti][1][g] >= 0.f) ? 1 : 0);
                rv += __shfl_xor(rv, 1);
                rv += __shfl_xor(rv, 2);
                rv += __shfl_xor(rv, 4);
                rv += __shfl_xor(rv, 8);
                if (nl == 0) atomicAdd(&rowc[wm * 64 + ti * 16 + rg * 4 + g], rv);
            }
    }
    __syncthreads();
    if (tid < 128) {
        atomicAdd(&counts[j0 + tid], colc[tid]);
        if (bi != bj) atomicAdd(&counts[i0 + tid], rowc[tid]);
    }
}

// ---------------- shared helpers ----------------
__device__ __forceinline__ int block_sum256(int v, int lane, int w, int* wred) {
#pragma unroll
    for (int o = 1; o < 64; o <<= 1) v += __shfl_xor(v, o);
    if (lane == 0) wred[w] = v;
    __syncthreads();
    int tt = wred[0] + wred[1] + wred[2] + wred[3];
    __syncthreads();
    return tt;
}
__device__ __forceinline__ int block_exscan256(int v, int lane, int w, int* wred,
                                               int* total) {
    int inc = v;
#pragma unroll
    for (int o = 1; o < 64; o <<= 1) { int u = __shfl_up(inc, o); if (lane >= o) inc += u; }
    if (lane == 63) wred[w] = inc;
    __syncthreads();
    int w0 = wred[0], w1 = wred[1], w2 = wred[2], w3 = wred[3];
    int wofs = (w > 0 ? w0 : 0) + (w > 1 ? w1 : 0) + (w > 2 ? w2 : 0);
    *total = w0 + w1 + w2 + w3;
    __syncthreads();
    return wofs + inc - v;   // exclusive
}

// ---------------- kernel 3: argmin seed (redundant/block) + simrow + zero outp ----------------
__global__ __launch_bounds__(256) void k_seedrow(const float* __restrict__ A,
                                                 const int* __restrict__ counts,
                                                 const int* __restrict__ attn_seed,
                                                 float* __restrict__ simrow,
                                                 int* __restrict__ seedp,
                                                 int* __restrict__ outp) {
    __shared__ int redA[256], redB[256];
    int tid = threadIdx.x, lane = tid & 63, w = tid >> 6;
    int blk = blockIdx.x;

    int bc = 0x7fffffff, bI = 0;
    for (int j = tid; j < NP; j += 256) {
        int c = counts[j];
        if (c < bc) { bc = c; bI = j; }
    }
    redA[tid] = bc; redB[tid] = bI;
    __syncthreads();
    for (int st = 128; st > 0; st >>= 1) {
        if (tid < st) {
            if (redA[tid + st] < redA[tid] ||
                (redA[tid + st] == redA[tid] && redB[tid + st] < redB[tid])) {
                redA[tid] = redA[tid + st];
                redB[tid] = redB[tid + st];
            }
        }
        __syncthreads();
    }
    int flat = redB[0];
    int sr = flat / WD, sc = flat % WD;
    int vr = sr + attn_seed[0];
    int vc = sc + attn_seed[1];
    int rr, rc;
    if ((vr & 1) == 0) rr = vr >> 1;
    else { int m = vr >> 1; rr = (m & 1) ? m + 1 : m; }   // round-half-to-even
    if ((vc & 1) == 0) rc = vc >> 1;
    else { int m = vc >> 1; rc = (m & 1) ? m + 1 : m; }
    int seed = rr * WD + rc;
    if (blk == 0 && tid == 0) seedp[0] = seed;

    float sv[12];
#pragma unroll
    for (int kk = 0; kk < 12; ++kk) sv[kk] = A[(size_t)seed * DD + lane + kk * 64];
    int jbase = blk * 32 + w * 8;
    for (int jj = 0; jj < 8; ++jj) {
        int j = jbase + jj;
        float sum = 0.f;
#pragma unroll
        for (int kk = 0; kk < 12; ++kk)
            sum += sv[kk] * A[(size_t)j * DD + lane + kk * 64];
#pragma unroll
        for (int o = 32; o > 0; o >>= 1) sum += __shfl_down(sum, o);
        if (lane == 0) simrow[j] = sum;
    }
    if (tid < 32) outp[blk * 32 + tid] = 0;
}

// ---------------- kernel 4: top-K select + compact (1 block) ----------------
__global__ __launch_bounds__(256) void k_sel(const float* __restrict__ simrow,
                                             const int* __restrict__ seedp,
                                             int* __restrict__ act, int* __restrict__ Mp) {
    __shared__ int wred[4];
    int tid = threadIdx.x, lane = tid & 63, w = tid >> 6;
    int seed = seedp[0];
    int base = tid * 16;
    unsigned key[16];
#pragma unroll
    for (int n = 0; n < 16; ++n) {
        unsigned b = __float_as_uint(simrow[base + n]);
        key[n] = (b & 0x80000000u) ? ~b : (b | 0x80000000u);   // monotone encode
    }
    unsigned prefix = 0;
    for (int bit = 31; bit >= 0; --bit) {
        unsigned cand = prefix | (1u << bit);
        int c = 0;
#pragma unroll
        for (int n = 0; n < 16; ++n) c += (key[n] >= cand) ? 1 : 0;
        int tot = block_sum256(c, lane, w, wred);
        if (tot >= KTOP) prefix = cand;
    }
    unsigned KT = prefix;
    int cgt = 0, ceq = 0;
#pragma unroll
    for (int n = 0; n < 16; ++n) {
        cgt += (key[n] > KT) ? 1 : 0;
        ceq += (key[n] == KT) ? 1 : 0;
    }
    int totgt = block_sum256(cgt, lane, w, wred);
    int slots = KTOP - totgt;
    int dummy;
    int eqrun = block_exscan256(ceq, lane, w, wred, &dummy);
    int flag[16]; int cf = 0;
#pragma unroll
    for (int n = 0; n < 16; ++n) {
        int j = base + n;
        unsigned k = key[n];
        int topk = (k > KT) || (k == KT && eqrun < slots);
        if (k == KT) ++eqrun;
        int f = (topk && (k >= 0x80000000u || j == seed)) ? 1 : 0;
        flag[n] = f; cf += f;
    }
    int M;
    int off = block_exscan256(cf, lane, w, wred, &M);
    if (tid == 0) Mp[0] = M;
#pragma unroll
    for (int n = 0; n < 16; ++n)
        if (flag[n]) act[off++] = base + n;
}

// ---------------- kernel 5: subsim rows ----------------
__global__ __launch_bounds__(256) void k_sub(const float* __restrict__ A,
                                             const int* __restrict__ act,
                                             const int* __restrict__ Mp,
                                             float* __restrict__ subsim) {
    __shared__ float av[DD];
    int M = Mp[0];
    int p = blockIdx.x;
    if (p >= M) return;
    int tid = threadIdx.x, lane = tid & 63, w = tid >> 6;
    int ip = act[p];
    for (int k = tid; k < DD; k += 256) av[k] = A[(size_t)ip * DD + k];
    __syncthreads();
    for (int q = w; q < M; q += 4) {
        int iq = act[q];
        float sum = 0.f;
#pragma unroll
        for (int kk = 0; kk < 12; ++kk) {
            int k = lane + kk * 64;
            sum += av[k] * A[(size_t)iq * DD + k];
        }
#pragma unroll
        for (int o = 32; o > 0; o >>= 1) sum += __shfl_down(sum, o);
        if (lane == 0) subsim[p * 128 + q] = sum;
    }
}

// ---------------- kernel 6: expansion scan + CC (1 block) ----------------
__global__ __launch_bounds__(256) void k_fin(const float* __restrict__ subsim,
                                             const int* __restrict__ act,
                                             const int* __restrict__ Mp,
                                             int* __restrict__ outp) {
    __shared__ float ss[128 * 128];   // 64 KB, transposed+rotated
    __shared__ int act_s[128];
    __shared__ int alive[128];
    __shared__ int lab[128];
    __shared__ unsigned char nbr[128][8];
    __shared__ int ncnt[128];
    __shared__ int chg;
    int M = Mp[0];
    int tid = threadIdx.x, lane = tid & 63;

    if (tid < 128) act_s[tid] = (tid < M) ? act[tid] : 0;
    // ssT(q,p) at ss[q*128 + ((p+q)&127)]: conflict-free writes & column reads
    for (int idx = tid; idx < M * 128; idx += 256) {
        int p = idx >> 7, q = idx & 127;
        ss[q * 128 + ((p + q) & 127)] = subsim[idx];
    }
    __syncthreads();

    // expansion scan with incremental sums
    if (tid < 64) {
        float S_lo = 0.f, S_hi = 0.f;
        for (int q = 0; q < M; ++q) {
            S_lo += ss[q * 128 + ((lane + q) & 127)];
            S_hi += ss[q * 128 + ((lane + 64 + q) & 127)];
        }
        float al = (lane < M) ? 1.f : 0.f;
        float ah = (lane + 64 < M) ? 1.f : 0.f;
        for (int p = 0; p < M; ++p) {
            float Sp = (p < 64) ? __shfl(S_lo, p) : __shfl(S_hi, p - 64);
            if (!(Sp > 0.f)) {   // node p dies: remove its column from all sums
                S_lo -= ss[p * 128 + ((lane + p) & 127)];
                S_hi -= ss[p * 128 + ((lane + 64 + p) & 127)];
                if (lane == p)      al = 0.f;
                if (lane + 64 == p) ah = 0.f;
            }
        }
        alive[lane]      = (lane < M && al != 0.f) ? 1 : 0;
        alive[lane + 64] = (lane + 64 < M && ah != 0.f) ? 1 : 0;
    }
    __syncthreads();

    // CC: neighbor lists + hook/pointer-jump
    if (tid < 128) {
        int a = (tid < M) ? alive[tid] : 0;
        int c = 0;
        if (a) {
            int id = act_s[tid];
            int y = id >> 6, x = id & 63;
            for (int q = 0; q < M; ++q) {
                if (q == tid || !alive[q]) continue;
                int qid = act_s[q];
                int dy = (qid >> 6) - y, dx = (qid & 63) - x;
                if (dy >= -1 && dy <= 1 && dx >= -1 && dx <= 1)
                    nbr[tid][c++] = (unsigned char)q;
            }
        }
        ncnt[tid] = c;
        lab[tid] = a ? tid : 32767;
    }
    __syncthreads();
    while (true) {
        if (tid == 0) chg = 0;
        __syncthreads();
        int local = 0;
        if (tid < M && alive[tid]) {
            int m = lab[tid];
            int nc = ncnt[tid];
            for (int k = 0; k < nc; ++k) { int u = lab[nbr[tid][k]]; if (u < m) m = u; }
            { int u = lab[m]; if (u < m) m = u; }   // jump
            { int u = lab[m]; if (u < m) m = u; }   // jump again
            if (m < lab[tid]) { lab[tid] = m; local = 1; }
        }
        if (local) chg = 1;
        __syncthreads();
        if (chg == 0) break;
        __syncthreads();
    }
    if (tid < M && alive[tid]) outp[act_s[tid]] = act_s[lab[tid]] + 1;
}

extern "C" void kernel_launch(void* const* d_in, const int* in_sizes, int n_in,
                              void* d_out, int out_size, void* d_ws, size_t ws_size,
                              hipStream_t stream) {
    const float* A = (const float*)d_in[0];       // out: (4096, 768) fp32
    const int* attn = (const int*)d_in[1];        // attn_seed: (2,) int32
    int* outp = (int*)d_out;                      // labels: (64,64) int32

    char* ws = (char*)d_ws;
    int*            counts = (int*)(ws);                    // 16 KB
    float*          simrow = (float*)(ws + 16384);          // 16 KB
    int*            act    = (int*)(ws + 32768);            // 512 B
    int*            Mp     = (int*)(ws + 33280);
    int*            seedp  = (int*)(ws + 33284);
    float*          subsim = (float*)(ws + 33792);          // 64 KB
    unsigned short* hi     = (unsigned short*)(ws + 1048576);           // 6.29 MB
    unsigned short* lo     = (unsigned short*)(ws + 1048576 + 6291456); // 6.29 MB

    k_split  <<<3072, 256, 0, stream>>>(A, hi, lo, counts);
    k_gemm   <<<528,  512, 0, stream>>>(hi, lo, counts);
    k_seedrow<<<128,  256, 0, stream>>>(A, counts, attn, simrow, seedp, outp);
    k_sel    <<<1,    256, 0, stream>>>(simrow, seedp, act, Mp);
    k_sub    <<<128,  256, 0, stream>>>(A, act, Mp, subsim);
    k_fin    <<<1,    256, 0, stream>>>(subsim, act, Mp, outp);
}